// Round 1
// baseline (167.149 us; speedup 1.0000x reference)
//
#include <hip/hip_runtime.h>

// Problem: B=16, PATCH_NUM=32, PATCH_SIZE=128, H=8, E=64, WIN=4096
// out[b,l,h,e] = V_inter[b, l>>7, h, e] + V_intra[b, l>>5, h, e]
// V_* are full-softmax attentions (scale = 1/8) over L=32 / L=128.
//
// Round 9 -> 10: FUSION. The two-kernel structure serialized device-wide
// (134 MB output sweep waits for ALL attention blocks) and round-tripped
// 10 MB of workspace. Observation: intra tile (b,h,tile) needs inter rows
// [tile*8, tile*8+8) exactly -- a disjoint partition across tiles, so the
// inter attention moves into the intra blocks with ZERO redundant compute.
// PV result goes to LDS (aliasing dead score region); each block then does
// its own duplicate+add sweep with nontemporal stores. One kernel, no ws.

#define NH 8
#define NE 64
#define ROWSTRIDE 512   // floats between consecutive l for fixed (b,h)

typedef float  vf4 __attribute__((ext_vector_type(4)));
typedef short  v8s __attribute__((ext_vector_type(8)));

__device__ __forceinline__ float dot4(const float4 a, const float4 b) {
    return a.x * b.x + a.y * b.y + a.z * b.z + a.w * b.w;
}

__device__ __forceinline__ unsigned short f2bf(float f) {   // RNE fp32->bf16
    unsigned int u = __float_as_uint(f);
    u += 0x7fff + ((u >> 16) & 1);
    return (unsigned short)(u >> 16);
}

// ---------------- LDS map (bytes) ----------------
// region1 [0, 23040):  sKb bf16[128][72] | sQb bf16[32][72] @18432
//                      alias after QK frag reads: sS fp32[32][132] (16896)
//                      alias after softmax:       sO fp32[32][68]  (8704)
// region2 [23040, 49152): sVb bf16[64][136] = V^T | sP bf16[32][136] @40448
// region3 [49152, 51200): sOI fp32[8][64] -- inter-attention output rows
#define SMEM_BYTES 51200
#define OFF_QB  18432
#define OFF_VB  23040
#define OFF_P   40448
#define OFF_OI  49152

__global__ __launch_bounds__(256, 2) void attn_fused(
    const float* __restrict__ qI, const float* __restrict__ kI, const float* __restrict__ vI,
    const float* __restrict__ qT, const float* __restrict__ kT, const float* __restrict__ vT,
    float* __restrict__ out)
{
    __shared__ __align__(16) char smem[SMEM_BYTES];
    const int tid  = threadIdx.x;
    const int ib   = blockIdx.x;          // 0..511
    const int tile = ib & 3;
    const int h    = (ib >> 2) & 7;
    const int b    = ib >> 5;
    const int r0   = tile * 32;           // first intra q-row of this tile

    // ---- 1. stage K,Q (bf16 row-major) + V^T (bf16); loads batched first ----
    {
        const float* kg = kT + ((size_t)b * 128 * NH + h) * NE;
        const float* vg = vT + ((size_t)b * 128 * NH + h) * NE;
        const float* qg = qT + ((size_t)(b * 128 + r0) * NH + h) * NE;

        float4 kr[8], vr[8], qr[2];
        #pragma unroll
        for (int i = 0; i < 8; i++) {
            const int idx = tid + i * 256;
            const int row = idx >> 4, f = (idx & 15) * 4;
            kr[i] = *(const float4*)(kg + (size_t)row * ROWSTRIDE + f);
        }
        #pragma unroll
        for (int i = 0; i < 8; i++) {
            const int idx = tid + i * 256;
            const int row = idx >> 4, f = (idx & 15) * 4;
            vr[i] = *(const float4*)(vg + (size_t)row * ROWSTRIDE + f);
        }
        #pragma unroll
        for (int i = 0; i < 2; i++) {
            const int idx = tid + i * 256;
            const int row = idx >> 4, f = (idx & 15) * 4;
            qr[i] = *(const float4*)(qg + (size_t)row * ROWSTRIDE + f);
        }

        unsigned short* wKb = (unsigned short*)smem;            // [128][72]
        #pragma unroll
        for (int i = 0; i < 8; i++) {
            const int idx = tid + i * 256;
            const int row = idx >> 4, f = (idx & 15) * 4;
            ushort4 pk; pk.x = f2bf(kr[i].x); pk.y = f2bf(kr[i].y);
            pk.z = f2bf(kr[i].z); pk.w = f2bf(kr[i].w);
            *(ushort4*)(wKb + row * 72 + f) = pk;
        }
        unsigned short* wQb = (unsigned short*)(smem + OFF_QB); // [32][72]
        #pragma unroll
        for (int i = 0; i < 2; i++) {
            const int idx = tid + i * 256;
            const int row = idx >> 4, f = (idx & 15) * 4;
            ushort4 pk; pk.x = f2bf(qr[i].x); pk.y = f2bf(qr[i].y);
            pk.z = f2bf(qr[i].z); pk.w = f2bf(qr[i].w);
            *(ushort4*)(wQb + row * 72 + f) = pk;
        }
        unsigned short* wVb = (unsigned short*)(smem + OFF_VB); // [64][136] = V^T
        #pragma unroll
        for (int i = 0; i < 8; i++) {
            const int idx = tid + i * 256;
            const int c = idx >> 4, f = (idx & 15) * 4;
            const float arr[4] = { vr[i].x, vr[i].y, vr[i].z, vr[i].w };
            #pragma unroll
            for (int u = 0; u < 4; u++) {
                const int j = (c + u) & 3;          // rotate to spread banks
                wVb[(f + j) * 136 + c] = f2bf(arr[j]);
            }
        }
    }

    // ---- 1b. inter attention, 8 rows x 32 cols (disjoint across tiles) ----
    // 8 groups of 32 lanes; group rg owns inter q-row tile*8+rg. Reads are
    // tiny (18 KB/block) and L2-resident; overlaps the LDS staging drain.
    {
        const int rg = tid >> 5;     // 0..7
        const int ln = tid & 31;
        const int hw = tid & 32;     // half-wave base within the 64-lane wave
        const int irow = tile * 8 + rg;
        const float* qrow = qI + ((size_t)(b * 32 + irow) * NH + h) * NE;
        const float* krow = kI + ((size_t)(b * 32 + ln)   * NH + h) * NE;
        float s = 0.f;
        #pragma unroll
        for (int e = 0; e < NE; e += 4)
            s += dot4(*(const float4*)(qrow + e), *(const float4*)(krow + e));
        s *= 0.125f;
        float m = s;
        #pragma unroll
        for (int msk = 1; msk < 32; msk <<= 1) m = fmaxf(m, __shfl_xor(m, msk));
        const float pe = __expf(s - m);
        float sum = pe;
        #pragma unroll
        for (int msk = 1; msk < 32; msk <<= 1) sum += __shfl_xor(sum, msk);
        const float pn = pe / sum;

        float o0 = 0.f, o1 = 0.f;
        const float* vg = vI + ((size_t)b * 32 * NH + h) * NE;
        #pragma unroll 8
        for (int c = 0; c < 32; c++) {
            const float pc = __shfl(pn, hw + c);
            const float2 v = *(const float2*)(vg + (size_t)c * ROWSTRIDE + ln * 2);
            o0 += pc * v.x;
            o1 += pc * v.y;
        }
        float* sOI = (float*)(smem + OFF_OI);   // [8][64]
        float2 o2; o2.x = o0; o2.y = o1;
        *(float2*)(sOI + rg * 64 + ln * 2) = o2;
    }
    __syncthreads();

    // ---- 2. MFMA scores: D(32x128) = Q(32x64) . K^T(64x128) ----
    const int lane = tid & 63;
    const int ln15 = lane & 15;
    const int quad = lane >> 4;
    const int w    = tid >> 6;      // wave 0..3
    const int mt   = w & 1;         // M-tile (16 q-rows)
    const int ntb  = (w >> 1) * 4;  // first of 4 N-tiles (16 kv-rows each)

    vf4 accS[4];
    #pragma unroll
    for (int t = 0; t < 4; t++) accS[t] = (vf4){0.f, 0.f, 0.f, 0.f};
    {
        const unsigned short* sKb = (const unsigned short*)smem;
        const unsigned short* sQb = (const unsigned short*)(smem + OFF_QB);
        #pragma unroll
        for (int kt = 0; kt < 2; kt++) {
            const v8s aQ = *(const v8s*)(sQb + (mt * 16 + ln15) * 72 + kt * 32 + quad * 8);
            #pragma unroll
            for (int t = 0; t < 4; t++) {
                const v8s bK = *(const v8s*)(sKb + ((ntb + t) * 16 + ln15) * 72 + kt * 32 + quad * 8);
                accS[t] = __builtin_amdgcn_mfma_f32_16x16x32_bf16(aQ, bK, accS[t], 0, 0, 0);
            }
        }
    }
    __syncthreads();   // all frag reads done; region1 dead -> becomes sS

    // ---- 3. scatter scaled scores to sS fp32[32][132] (C-layout) ----
    {
        float* sS = (float*)smem;
        #pragma unroll
        for (int t = 0; t < 4; t++)
            #pragma unroll
            for (int reg = 0; reg < 4; reg++)
                sS[(mt * 16 + quad * 4 + reg) * 132 + (ntb + t) * 16 + ln15]
                    = accS[t][reg] * 0.125f;
    }
    __syncthreads();

    // ---- 4. softmax (fp32) -> normalized P bf16[32][136] ----
    {
        const float* sS = (const float*)smem;
        unsigned short* sP = (unsigned short*)(smem + OFF_P);
        const int r   = tid >> 3;
        const int sub = tid & 7;
        float vals[16];
        const float* Srow = sS + r * 132 + sub * 16;
        #pragma unroll
        for (int c4 = 0; c4 < 4; c4++) {
            const float4 v = *(const float4*)(Srow + c4 * 4);
            vals[c4*4+0] = v.x; vals[c4*4+1] = v.y; vals[c4*4+2] = v.z; vals[c4*4+3] = v.w;
        }
        float m = vals[0];
        #pragma unroll
        for (int i = 1; i < 16; i++) m = fmaxf(m, vals[i]);
        #pragma unroll
        for (int msk = 1; msk < 8; msk <<= 1) m = fmaxf(m, __shfl_xor(m, msk));
        float s = 0.f;
        #pragma unroll
        for (int i = 0; i < 16; i++) { vals[i] = __expf(vals[i] - m); s += vals[i]; }
        #pragma unroll
        for (int msk = 1; msk < 8; msk <<= 1) s += __shfl_xor(s, msk);
        const float inv = 1.f / s;
        #pragma unroll
        for (int c4 = 0; c4 < 4; c4++) {
            ushort4 pk;
            pk.x = f2bf(vals[c4*4+0] * inv); pk.y = f2bf(vals[c4*4+1] * inv);
            pk.z = f2bf(vals[c4*4+2] * inv); pk.w = f2bf(vals[c4*4+3] * inv);
            *(ushort4*)(sP + r * 136 + sub * 16 + c4 * 4) = pk;
        }
    }
    __syncthreads();   // sS dead -> region1 front becomes sO

    // ---- 5. MFMA PV: O(32x64) = P(32x128) . V(128x64) -> sO (LDS) ----
    {
        const unsigned short* sVb = (const unsigned short*)(smem + OFF_VB);
        const unsigned short* sP  = (const unsigned short*)(smem + OFF_P);
        float* sO = (float*)smem;       // [32][68] f32
        const int neb = (w >> 1) * 2;   // first of 2 N-tiles (16 e each)

        vf4 accO[2];
        accO[0] = (vf4){0.f, 0.f, 0.f, 0.f};
        accO[1] = (vf4){0.f, 0.f, 0.f, 0.f};
        #pragma unroll
        for (int kt = 0; kt < 4; kt++) {
            const v8s aP = *(const v8s*)(sP + (mt * 16 + ln15) * 136 + kt * 32 + quad * 8);
            #pragma unroll
            for (int t = 0; t < 2; t++) {
                const v8s bV = *(const v8s*)(sVb + ((neb + t) * 16 + ln15) * 136 + kt * 32 + quad * 8);
                accO[t] = __builtin_amdgcn_mfma_f32_16x16x32_bf16(aP, bV, accO[t], 0, 0, 0);
            }
        }
        #pragma unroll
        for (int t = 0; t < 2; t++) {
            const int e = (neb + t) * 16 + ln15;
            #pragma unroll
            for (int reg = 0; reg < 4; reg++) {
                const int row = mt * 16 + quad * 4 + reg;   // local 0..31
                sO[row * 68 + e] = accO[t][reg];
            }
        }
    }
    __syncthreads();

    // ---- 6. duplicate+add sweep: out[b,(r0+r)*32+j,h,:] = sO[r] + sOI[r>>2] ----
    {
        const float* sO  = (const float*)smem;
        const float* sOI = (const float*)(smem + OFF_OI);
        const int e4 = tid & 15;
        const int rr = tid >> 4;     // 0..15
        #pragma unroll
        for (int p = 0; p < 2; p++) {
            const int r = rr + p * 16;                       // local row 0..31
            const float4 a  = *(const float4*)(sO  + r * 68 + e4 * 4);
            const float4 cI = *(const float4*)(sOI + (r >> 2) * 64 + e4 * 4);
            vf4 s; s.x = a.x + cI.x; s.y = a.y + cI.y;
            s.z = a.z + cI.z; s.w = a.w + cI.w;
            float* o = out + (((size_t)b * 4096 + (size_t)(r0 + r) * 32) * NH + h) * NE + e4 * 4;
            #pragma unroll
            for (int j = 0; j < 32; j++)
                __builtin_nontemporal_store(s, (vf4*)(o + (size_t)j * ROWSTRIDE));
        }
    }
}

extern "C" void kernel_launch(void* const* d_in, const int* in_sizes, int n_in,
                              void* d_out, int out_size, void* d_ws, size_t ws_size,
                              hipStream_t stream) {
    const float* q_inter = (const float*)d_in[0];
    const float* k_inter = (const float*)d_in[1];
    const float* v_inter = (const float*)d_in[2];
    const float* q_intra = (const float*)d_in[3];
    const float* k_intra = (const float*)d_in[4];
    const float* v_intra = (const float*)d_in[5];
    float* out = (float*)d_out;

    // Single fused kernel: 512 blocks (b,h,tile), 2 blocks/CU co-resident.
    attn_fused<<<512, 256, 0, stream>>>(
        q_inter, k_inter, v_inter, q_intra, k_intra, v_intra, out);
}